// Round 4
// baseline (1831.722 us; speedup 1.0000x reference)
//
#include <hip/hip_runtime.h>
#include <math.h>

#define N_NODES 100000
#define N_EDGES 1600000
#define N_B 64
#define D_IN 64
#define D_HID 128
#define D_OUT 128
#define K_ITER 16
#define LN_EPS 1e-5f

typedef short s8v __attribute__((ext_vector_type(8)));
typedef float f4v __attribute__((ext_vector_type(4)));

__device__ __forceinline__ float gelu_f(float x) {
    return 0.5f * x * (1.0f + erff(0.70710678118654752440f * x));
}

__device__ __forceinline__ float ubx(unsigned u) { return __uint_as_float(u << 16); }
__device__ __forceinline__ float uby(unsigned u) { return __uint_as_float(u & 0xffff0000u); }

__device__ __forceinline__ unsigned short bf_rne(float x) {
    unsigned u = __float_as_uint(x);
    u += 0x7fffu + ((u >> 16) & 1u);
    return (unsigned short)(u >> 16);
}
__device__ __forceinline__ float bf_f(unsigned short s) {
    return __uint_as_float(((unsigned)s) << 16);
}
__device__ __forceinline__ unsigned pack_bf2(float a, float b) {
    return (unsigned)bf_rne(a) | (((unsigned)bf_rne(b)) << 16);
}

// ---------------- CSR build ----------------

__global__ __launch_bounds__(256) void hist_kernel(const int* __restrict__ dst, int* __restrict__ counts) {
    int e = blockIdx.x * 256 + threadIdx.x;
    if (e < N_EDGES) atomicAdd(&counts[dst[e]], 1);
}

__global__ __launch_bounds__(256) void deg_kernel(const int* __restrict__ counts,
                                                  float* __restrict__ dis, float* __restrict__ selfw,
                                                  float* __restrict__ rsq) {
    int i = blockIdx.x * 256 + threadIdx.x;
    if (i < N_NODES) {
        float d = (float)(counts[i] + 1);
        dis[i] = 1.0f / sqrtf(d);
        selfw[i] = 1.0f / d;
        rsq[i] = sqrtf(d);
    }
}

__global__ __launch_bounds__(1024) void scan1(const int* __restrict__ counts, int* __restrict__ rp,
                                              int* __restrict__ bsum) {
    __shared__ int tmp[1024];
    int t = threadIdx.x;
    int idx = blockIdx.x * 1024 + t;
    int v = (idx < N_NODES) ? counts[idx] : 0;
    tmp[t] = v;
    __syncthreads();
    for (int o = 1; o < 1024; o <<= 1) {
        int add = (t >= o) ? tmp[t - o] : 0;
        __syncthreads();
        tmp[t] += add;
        __syncthreads();
    }
    if (idx < N_NODES) rp[idx] = tmp[t] - v;   // exclusive
    if (t == 1023) bsum[blockIdx.x] = tmp[t];
}

__global__ void scan2(int* bsum, int nb) {
    if (threadIdx.x == 0 && blockIdx.x == 0) {
        int acc = 0;
        for (int i = 0; i < nb; i++) { int v = bsum[i]; bsum[i] = acc; acc += v; }
    }
}

__global__ __launch_bounds__(1024) void scan3(int* __restrict__ rp, const int* __restrict__ bsum,
                                              int* __restrict__ cursor) {
    int t = threadIdx.x;
    int idx = blockIdx.x * 1024 + t;
    if (idx < N_NODES) {
        int v = rp[idx] + bsum[blockIdx.x];
        rp[idx] = v;
        cursor[idx] = v;
    }
    if (idx == 0) rp[N_NODES] = N_EDGES;
}

// Single 16B store per edge: {src, ea.x, ea.y, 0}. One cache line touched per edge.
__global__ __launch_bounds__(256) void scatter_kernel(const int* __restrict__ src, const int* __restrict__ dst,
                                                      const float* __restrict__ ea,
                                                      int* __restrict__ cursor, int4* __restrict__ edata) {
    int e = blockIdx.x * 256 + threadIdx.x;
    if (e >= N_EDGES) return;
    int s = src[e], d = dst[e];
    int pos = atomicAdd(&cursor[d], 1);
    float2 e2 = ((const float2*)ea)[e];
    int4 v;
    v.x = s;
    v.y = __float_as_int(e2.x);
    v.z = __float_as_int(e2.y);
    v.w = 0;
    edata[pos] = v;
}

// Compact 4B/edge src stream for APPNP (coalesced read+write).
__global__ __launch_bounds__(256) void split_kernel(const int4* __restrict__ edata, int* __restrict__ esrc) {
    int e = blockIdx.x * 256 + threadIdx.x;
    if (e < N_EDGES) esrc[e] = edata[e].x;
}

// x (f32 [N,64]) -> bf16 copy for conv1 message gathers (halves gather bytes).
__global__ __launch_bounds__(256) void x_to_bf(const float4* __restrict__ x4, uint2* __restrict__ xb2) {
    int i = blockIdx.x * 256 + threadIdx.x;
    if (i < N_NODES * 16) {
        float4 v = x4[i];
        uint2 o;
        o.x = pack_bf2(v.x, v.y);
        o.y = pack_bf2(v.z, v.w);
        xb2[i] = o;
    }
}

// ---------------- GINE gathers (wide-lane: one VMEM instruction fetches multiple rows) ----------------

// conv1: octet-wave layout. Row = 64 bf16 = 128B. Each lane loads uint4 (16B = 8 features);
// 8 lanes cover a row; 8 edges per gather instruction. Merge via shfl_xor(8/16/32).
__global__ __launch_bounds__(256) void conv1_gather(const float* __restrict__ x,
                                                    const unsigned* __restrict__ xb,
                                                    const int* __restrict__ rp,
                                                    const int4* __restrict__ edata,
                                                    const float* __restrict__ We1, const float* __restrict__ be1,
                                                    float* __restrict__ out) {
    int gw = (blockIdx.x * 256 + threadIdx.x) >> 6;
    if (gw >= N_NODES) return;
    int lane = threadIdx.x & 63;
    int oct = lane >> 3;       // 0..7: which edge in group
    int sl = lane & 7;         // which 16B chunk of row (features sl*8 .. sl*8+7)
    float w0c[8], w1c[8], bc[8];
    #pragma unroll
    for (int t = 0; t < 8; t++) {
        int col = sl * 8 + t;
        w0c[t] = We1[col];
        w1c[t] = We1[64 + col];
        bc[t] = be1[col];
    }
    float a[8];
    #pragma unroll
    for (int t = 0; t < 8; t++) a[t] = 0.f;

#define C1ACC(E, V)                                                              \
    {                                                                            \
        float eax = __int_as_float((E).y), eay = __int_as_float((E).z);          \
        a[0] += fmaxf(ubx((V).x) + eax * w0c[0] + eay * w1c[0] + bc[0], 0.f);    \
        a[1] += fmaxf(uby((V).x) + eax * w0c[1] + eay * w1c[1] + bc[1], 0.f);    \
        a[2] += fmaxf(ubx((V).y) + eax * w0c[2] + eay * w1c[2] + bc[2], 0.f);    \
        a[3] += fmaxf(uby((V).y) + eax * w0c[3] + eay * w1c[3] + bc[3], 0.f);    \
        a[4] += fmaxf(ubx((V).z) + eax * w0c[4] + eay * w1c[4] + bc[4], 0.f);    \
        a[5] += fmaxf(uby((V).z) + eax * w0c[5] + eay * w1c[5] + bc[5], 0.f);    \
        a[6] += fmaxf(ubx((V).w) + eax * w0c[6] + eay * w1c[6] + bc[6], 0.f);    \
        a[7] += fmaxf(uby((V).w) + eax * w0c[7] + eay * w1c[7] + bc[7], 0.f);    \
    }

    int j = rp[gw], jend = rp[gw + 1];
    for (; j + 16 <= jend; j += 16) {
        int4 e0 = edata[j + oct];
        int4 e1 = edata[j + 8 + oct];
        uint4 v0 = *((const uint4*)(xb + (size_t)e0.x * 32) + sl);
        uint4 v1 = *((const uint4*)(xb + (size_t)e1.x * 32) + sl);
        C1ACC(e0, v0);
        C1ACC(e1, v1);
    }
    for (; j + 8 <= jend; j += 8) {
        int4 e0 = edata[j + oct];
        uint4 v0 = *((const uint4*)(xb + (size_t)e0.x * 32) + sl);
        C1ACC(e0, v0);
    }
    int rem = jend - j;
    if (rem > 0) {
        int4 e0 = edata[j + ((oct < rem) ? oct : 0)];
        uint4 v0 = *((const uint4*)(xb + (size_t)e0.x * 32) + sl);
        if (oct < rem) C1ACC(e0, v0);
    }
#undef C1ACC
    #pragma unroll
    for (int t = 0; t < 8; t++) {
        a[t] += __shfl_xor(a[t], 8, 64);
        a[t] += __shfl_xor(a[t], 16, 64);
        a[t] += __shfl_xor(a[t], 32, 64);
    }
    if (lane < 8) {
        const float4* xr = (const float4*)(x + (size_t)gw * 64);
        float4 s0 = xr[sl * 2], s1 = xr[sl * 2 + 1];
        float4* orow = (float4*)(out + (size_t)gw * 64);
        float4 o0, o1;
        o0.x = a[0] + s0.x; o0.y = a[1] + s0.y; o0.z = a[2] + s0.z; o0.w = a[3] + s0.w;
        o1.x = a[4] + s1.x; o1.y = a[5] + s1.y; o1.z = a[6] + s1.z; o1.w = a[7] + s1.w;
        orow[sl * 2] = o0;
        orow[sl * 2 + 1] = o1;
    }
}

// conv2: quarter-wave layout. Row = 128 bf16 = 256B. Each lane loads uint4 (8 features);
// 16 lanes cover a row; 4 edges per gather instruction. Merge via shfl_xor(16/32).
__global__ __launch_bounds__(256) void conv2_gather(const float* __restrict__ h1f, const unsigned* __restrict__ h1b,
                                                    const int* __restrict__ rp,
                                                    const int4* __restrict__ edata,
                                                    const float* __restrict__ We2, const float* __restrict__ be2,
                                                    float* __restrict__ out) {
    int gw = (blockIdx.x * 256 + threadIdx.x) >> 6;
    if (gw >= N_NODES) return;
    int lane = threadIdx.x & 63;
    int quad = lane >> 4;      // 0..3: which edge in group
    int sl = lane & 15;        // which 16B chunk of row (features sl*8 .. sl*8+7)
    float w0c[8], w1c[8], bc[8];
    #pragma unroll
    for (int t = 0; t < 8; t++) {
        int col = sl * 8 + t;
        w0c[t] = We2[col];
        w1c[t] = We2[128 + col];
        bc[t] = be2[col];
    }
    float a[8];
    #pragma unroll
    for (int t = 0; t < 8; t++) a[t] = 0.f;

#define C2ACC(E, V)                                                              \
    {                                                                            \
        float eax = __int_as_float((E).y), eay = __int_as_float((E).z);          \
        a[0] += fmaxf(ubx((V).x) + eax * w0c[0] + eay * w1c[0] + bc[0], 0.f);    \
        a[1] += fmaxf(uby((V).x) + eax * w0c[1] + eay * w1c[1] + bc[1], 0.f);    \
        a[2] += fmaxf(ubx((V).y) + eax * w0c[2] + eay * w1c[2] + bc[2], 0.f);    \
        a[3] += fmaxf(uby((V).y) + eax * w0c[3] + eay * w1c[3] + bc[3], 0.f);    \
        a[4] += fmaxf(ubx((V).z) + eax * w0c[4] + eay * w1c[4] + bc[4], 0.f);    \
        a[5] += fmaxf(uby((V).z) + eax * w0c[5] + eay * w1c[5] + bc[5], 0.f);    \
        a[6] += fmaxf(ubx((V).w) + eax * w0c[6] + eay * w1c[6] + bc[6], 0.f);    \
        a[7] += fmaxf(uby((V).w) + eax * w0c[7] + eay * w1c[7] + bc[7], 0.f);    \
    }

    int j = rp[gw], jend = rp[gw + 1];
    for (; j + 16 <= jend; j += 16) {
        int4 e0 = edata[j + quad];
        int4 e1 = edata[j + 4 + quad];
        int4 e2 = edata[j + 8 + quad];
        int4 e3 = edata[j + 12 + quad];
        uint4 v0 = *((const uint4*)(h1b + (size_t)e0.x * 64) + sl);
        uint4 v1 = *((const uint4*)(h1b + (size_t)e1.x * 64) + sl);
        uint4 v2 = *((const uint4*)(h1b + (size_t)e2.x * 64) + sl);
        uint4 v3 = *((const uint4*)(h1b + (size_t)e3.x * 64) + sl);
        C2ACC(e0, v0);
        C2ACC(e1, v1);
        C2ACC(e2, v2);
        C2ACC(e3, v3);
    }
    for (; j + 8 <= jend; j += 8) {
        int4 e0 = edata[j + quad];
        int4 e1 = edata[j + 4 + quad];
        uint4 v0 = *((const uint4*)(h1b + (size_t)e0.x * 64) + sl);
        uint4 v1 = *((const uint4*)(h1b + (size_t)e1.x * 64) + sl);
        C2ACC(e0, v0);
        C2ACC(e1, v1);
    }
    for (; j + 4 <= jend; j += 4) {
        int4 e0 = edata[j + quad];
        uint4 v0 = *((const uint4*)(h1b + (size_t)e0.x * 64) + sl);
        C2ACC(e0, v0);
    }
    int rem = jend - j;
    if (rem > 0) {
        int4 e0 = edata[j + ((quad < rem) ? quad : 0)];
        uint4 v0 = *((const uint4*)(h1b + (size_t)e0.x * 64) + sl);
        if (quad < rem) C2ACC(e0, v0);
    }
#undef C2ACC
    #pragma unroll
    for (int t = 0; t < 8; t++) {
        a[t] += __shfl_xor(a[t], 16, 64);
        a[t] += __shfl_xor(a[t], 32, 64);
    }
    if (lane < 16) {
        const float4* hr = (const float4*)(h1f + (size_t)gw * 128);
        float4 s0 = hr[sl * 2], s1 = hr[sl * 2 + 1];
        float4* orow = (float4*)(out + (size_t)gw * 128);
        float4 o0, o1;
        o0.x = a[0] + s0.x; o0.y = a[1] + s0.y; o0.z = a[2] + s0.z; o0.w = a[3] + s0.w;
        o1.x = a[4] + s1.x; o1.y = a[5] + s1.y; o1.z = a[6] + s1.z; o1.w = a[7] + s1.w;
        orow[sl * 2] = o0;
        orow[sl * 2 + 1] = o1;
    }
}

// ---------------- MLP layers via MFMA (split-bf16: Ahi*Whi + Ahi*Wlo + Alo*Whi) ----------------
// OMODE: 0 = f32 out only, 1 = f32 + bf16 copy, 2 = bf16 only.
// SCALE: multiply bf16 output by uscale[row] (used to emit u0 = dis*h for APPNP).

template <int Kd, bool GELU, bool LN, int OMODE, bool SCALE>
__global__ __launch_bounds__(256) void mlp_mfma(const float* __restrict__ A, const float* __restrict__ W,
                                                const float* __restrict__ bias, const float* __restrict__ g,
                                                const float* __restrict__ bn, float* __restrict__ outf,
                                                unsigned short* __restrict__ outb,
                                                const float* __restrict__ uscale) {
    __shared__ unsigned short sHi[8192];   // 64 k-rows x 128 cols, swizzled
    __shared__ unsigned short sLo[8192];
    int wave = threadIdx.x >> 6, lane = threadIdx.x & 63;
    int quad = lane >> 4, n = lane & 15;
    int rowA = blockIdx.x * 64 + wave * 16 + n;
    int rowAc = (rowA < N_NODES) ? rowA : 0;

    f4v acc[8];
    #pragma unroll
    for (int t = 0; t < 8; t++) acc[t] = (f4v){0.f, 0.f, 0.f, 0.f};

    for (int ph = 0; ph < Kd / 64; ph++) {
        __syncthreads();
        for (int idx = threadIdx.x; idx < 8192; idx += 256) {
            int k = idx >> 7, c = idx & 127;
            float v = W[(size_t)(ph * 64 + k) * 128 + c];
            unsigned short hi = bf_rne(v);
            unsigned short lo = bf_rne(v - bf_f(hi));
            int kk = k >> 5, q = (k >> 3) & 3, j = k & 7, t = c >> 4, nn = c & 15;
            int lidx = ((((kk * 4 + q) * 8 + t) * 16 + nn) << 3) + j;
            sHi[lidx] = hi;
            sLo[lidx] = lo;
        }
        __syncthreads();
        #pragma unroll
        for (int kk = 0; kk < 2; kk++) {
            int k0 = ph * 64 + kk * 32 + quad * 8;
            const float4* ap = (const float4*)(A + (size_t)rowAc * Kd + k0);
            float4 a0 = ap[0], a1 = ap[1];
            float av[8] = {a0.x, a0.y, a0.z, a0.w, a1.x, a1.y, a1.z, a1.w};
            s8v ahi, alo;
            #pragma unroll
            for (int j = 0; j < 8; j++) {
                unsigned short h = bf_rne(av[j]);
                ahi[j] = (short)h;
                alo[j] = (short)bf_rne(av[j] - bf_f(h));
            }
            int base = ((kk * 4 + quad) * 8) * 128;
            #pragma unroll
            for (int t = 0; t < 8; t++) {
                s8v bhi = *(const s8v*)&sHi[base + ((t * 16 + n) << 3)];
                s8v blo = *(const s8v*)&sLo[base + ((t * 16 + n) << 3)];
                acc[t] = __builtin_amdgcn_mfma_f32_16x16x32_bf16(ahi, bhi, acc[t], 0, 0, 0);
                acc[t] = __builtin_amdgcn_mfma_f32_16x16x32_bf16(ahi, blo, acc[t], 0, 0, 0);
                acc[t] = __builtin_amdgcn_mfma_f32_16x16x32_bf16(alo, bhi, acc[t], 0, 0, 0);
            }
        }
    }

    float bcol[8], gcol[8], bncol[8];
    #pragma unroll
    for (int t = 0; t < 8; t++) {
        bcol[t] = bias[t * 16 + n];
        if (LN) { gcol[t] = g[t * 16 + n]; bncol[t] = bn[t * 16 + n]; }
    }
    #pragma unroll
    for (int r = 0; r < 4; r++) {
        int row = blockIdx.x * 64 + wave * 16 + quad * 4 + r;
        float v[8];
        #pragma unroll
        for (int t = 0; t < 8; t++) {
            float x = acc[t][r] + bcol[t];
            v[t] = GELU ? gelu_f(x) : x;
        }
        if (LN) {
            float s = 0.f, q2 = 0.f;
            #pragma unroll
            for (int t = 0; t < 8; t++) { s += v[t]; q2 += v[t] * v[t]; }
            #pragma unroll
            for (int m = 1; m <= 8; m <<= 1) {
                s += __shfl_xor(s, m, 64);
                q2 += __shfl_xor(q2, m, 64);
            }
            float mu = s * (1.0f / 128.0f);
            float rs = rsqrtf(q2 * (1.0f / 128.0f) - mu * mu + LN_EPS);
            #pragma unroll
            for (int t = 0; t < 8; t++) v[t] = (v[t] - mu) * rs * gcol[t] + bncol[t];
        }
        if (row < N_NODES) {
            float us = SCALE ? uscale[row] : 1.0f;
            #pragma unroll
            for (int t = 0; t < 8; t++) {
                if (OMODE != 2) outf[(size_t)row * 128 + t * 16 + n] = v[t];
                if (OMODE >= 1) outb[(size_t)row * 128 + t * 16 + n] = bf_rne(SCALE ? v[t] * us : v[t]);
            }
        }
    }
}

// ---------------- Gate via MFMA: gate = gelu(h@Wg1+bg1)@Wg2 + bg2 ----------------

__global__ __launch_bounds__(256) void gate_mfma(const float* __restrict__ h, const float* __restrict__ Wg1,
                                                 const float* __restrict__ bg1, const float* __restrict__ Wg2,
                                                 const float* __restrict__ bg2, float* __restrict__ gate) {
    __shared__ unsigned short sHi[8192];  // 128 k x 64 cols, swizzled
    __shared__ unsigned short sLo[8192];
    int wave = threadIdx.x >> 6, lane = threadIdx.x & 63;
    int quad = lane >> 4, n = lane & 15;
    for (int idx = threadIdx.x; idx < 8192; idx += 256) {
        int k = idx >> 6, c = idx & 63;
        float v = Wg1[k * 64 + c];
        unsigned short hi = bf_rne(v);
        unsigned short lo = bf_rne(v - bf_f(hi));
        int kk = k >> 5, q = (k >> 3) & 3, j = k & 7, t = c >> 4, nn = c & 15;
        int lidx = ((((kk * 4 + q) * 4 + t) * 16 + nn) << 3) + j;
        sHi[lidx] = hi;
        sLo[lidx] = lo;
    }
    __syncthreads();
    int rowA = blockIdx.x * 64 + wave * 16 + n;
    int rowAc = (rowA < N_NODES) ? rowA : 0;
    f4v acc[4];
    #pragma unroll
    for (int t = 0; t < 4; t++) acc[t] = (f4v){0.f, 0.f, 0.f, 0.f};
    #pragma unroll
    for (int kk = 0; kk < 4; kk++) {
        const float4* ap = (const float4*)(h + (size_t)rowAc * 128 + kk * 32 + quad * 8);
        float4 a0 = ap[0], a1 = ap[1];
        float av[8] = {a0.x, a0.y, a0.z, a0.w, a1.x, a1.y, a1.z, a1.w};
        s8v ahi, alo;
        #pragma unroll
        for (int j = 0; j < 8; j++) {
            unsigned short hh = bf_rne(av[j]);
            ahi[j] = (short)hh;
            alo[j] = (short)bf_rne(av[j] - bf_f(hh));
        }
        int base = ((kk * 4 + quad) * 4) * 128;
        #pragma unroll
        for (int t = 0; t < 4; t++) {
            s8v bhi = *(const s8v*)&sHi[base + ((t * 16 + n) << 3)];
            s8v blo = *(const s8v*)&sLo[base + ((t * 16 + n) << 3)];
            acc[t] = __builtin_amdgcn_mfma_f32_16x16x32_bf16(ahi, bhi, acc[t], 0, 0, 0);
            acc[t] = __builtin_amdgcn_mfma_f32_16x16x32_bf16(ahi, blo, acc[t], 0, 0, 0);
            acc[t] = __builtin_amdgcn_mfma_f32_16x16x32_bf16(alo, bhi, acc[t], 0, 0, 0);
        }
    }
    float b2 = bg2[0];
    float bb[4], vv[4];
    #pragma unroll
    for (int t = 0; t < 4; t++) { bb[t] = bg1[t * 16 + n]; vv[t] = Wg2[t * 16 + n]; }
    #pragma unroll
    for (int r = 0; r < 4; r++) {
        int row = blockIdx.x * 64 + wave * 16 + quad * 4 + r;
        float val = 0.f;
        #pragma unroll
        for (int t = 0; t < 4; t++) val += gelu_f(acc[t][r] + bb[t]) * vv[t];
        #pragma unroll
        for (int m = 1; m <= 8; m <<= 1) val += __shfl_xor(val, m, 64);
        if (n == 0 && row < N_NODES) gate[row] = val + b2;
    }
}

// ---------------- APPNP in scaled space u = dis*h ----------------
// u'_i = 0.9*selfw_i*(sum_j u_j + u_i) + 0.1*u0_i ; final h = u*rsq.
// Quarter-wave gathers: each lane loads uint4 (16B = 8 features); 16 lanes
// cover a 256B row; one instruction fetches FOUR edges' rows. Quarter-wave
// partial sums merged via shfl_xor(16/32).

template <bool LAST>
__global__ __launch_bounds__(256) void appnp_step_u(const unsigned* __restrict__ hin,
                                                    const unsigned* __restrict__ anchor,
                                                    unsigned* __restrict__ hout, float* __restrict__ houtf,
                                                    const int* __restrict__ rp, const int* __restrict__ esrc,
                                                    const float* __restrict__ selfw,
                                                    const float* __restrict__ rsq) {
    int gw = (blockIdx.x * 256 + threadIdx.x) >> 6;
    if (gw >= N_NODES) return;
    int lane = threadIdx.x & 63;
    int quad = lane >> 4;      // which edge in group of 4
    int sl = lane & 15;        // which 16B chunk of row
    float a[8];
    #pragma unroll
    for (int t = 0; t < 8; t++) a[t] = 0.f;

#define UACC(V)                                   \
    {                                             \
        a[0] += ubx((V).x); a[1] += uby((V).x);   \
        a[2] += ubx((V).y); a[3] += uby((V).y);   \
        a[4] += ubx((V).z); a[5] += uby((V).z);   \
        a[6] += ubx((V).w); a[7] += uby((V).w);   \
    }

    int j = rp[gw], jend = rp[gw + 1];
    for (; j + 16 <= jend; j += 16) {
        int s0 = esrc[j + quad];
        int s1 = esrc[j + 4 + quad];
        int s2 = esrc[j + 8 + quad];
        int s3 = esrc[j + 12 + quad];
        uint4 v0 = *((const uint4*)(hin + (size_t)s0 * 64) + sl);
        uint4 v1 = *((const uint4*)(hin + (size_t)s1 * 64) + sl);
        uint4 v2 = *((const uint4*)(hin + (size_t)s2 * 64) + sl);
        uint4 v3 = *((const uint4*)(hin + (size_t)s3 * 64) + sl);
        UACC(v0);
        UACC(v1);
        UACC(v2);
        UACC(v3);
    }
    for (; j + 8 <= jend; j += 8) {
        int s0 = esrc[j + quad];
        int s1 = esrc[j + 4 + quad];
        uint4 v0 = *((const uint4*)(hin + (size_t)s0 * 64) + sl);
        uint4 v1 = *((const uint4*)(hin + (size_t)s1 * 64) + sl);
        UACC(v0);
        UACC(v1);
    }
    for (; j + 4 <= jend; j += 4) {
        int s0 = esrc[j + quad];
        uint4 v0 = *((const uint4*)(hin + (size_t)s0 * 64) + sl);
        UACC(v0);
    }
    int rem = jend - j;
    if (rem > 0) {
        int s0 = esrc[j + ((quad < rem) ? quad : 0)];
        uint4 v0 = *((const uint4*)(hin + (size_t)s0 * 64) + sl);
        if (quad < rem) UACC(v0);
    }
#undef UACC
    #pragma unroll
    for (int t = 0; t < 8; t++) {
        a[t] += __shfl_xor(a[t], 16, 64);
        a[t] += __shfl_xor(a[t], 32, 64);
    }
    // self + anchor (wave-broadcast row loads)
    uint4 hc = *((const uint4*)(hin + (size_t)gw * 64) + sl);
    uint4 an = *((const uint4*)(anchor + (size_t)gw * 64) + sl);
    float swi = 0.9f * selfw[gw];
    float o[8];
    o[0] = fmaf(swi, a[0] + ubx(hc.x), 0.1f * ubx(an.x));
    o[1] = fmaf(swi, a[1] + uby(hc.x), 0.1f * uby(an.x));
    o[2] = fmaf(swi, a[2] + ubx(hc.y), 0.1f * ubx(an.y));
    o[3] = fmaf(swi, a[3] + uby(hc.y), 0.1f * uby(an.y));
    o[4] = fmaf(swi, a[4] + ubx(hc.z), 0.1f * ubx(an.z));
    o[5] = fmaf(swi, a[5] + uby(hc.z), 0.1f * uby(an.z));
    o[6] = fmaf(swi, a[6] + ubx(hc.w), 0.1f * ubx(an.w));
    o[7] = fmaf(swi, a[7] + uby(hc.w), 0.1f * uby(an.w));
    if (LAST) {
        if (lane < 16) {
            float rq = rsq[gw];
            float4* orow = (float4*)(houtf + (size_t)gw * 128);
            float4 w0, w1;
            w0.x = o[0] * rq; w0.y = o[1] * rq; w0.z = o[2] * rq; w0.w = o[3] * rq;
            w1.x = o[4] * rq; w1.y = o[5] * rq; w1.z = o[6] * rq; w1.w = o[7] * rq;
            orow[sl * 2] = w0;
            orow[sl * 2 + 1] = w1;
        }
    } else {
        if (lane < 16) {
            uint4 w;
            w.x = pack_bf2(o[0], o[1]);
            w.y = pack_bf2(o[2], o[3]);
            w.z = pack_bf2(o[4], o[5]);
            w.w = pack_bf2(o[6], o[7]);
            *((uint4*)(hout + (size_t)gw * 64) + sl) = w;
        }
    }
}

// ---------------- Attentional pooling ----------------

__global__ void seg_begin(const int* __restrict__ batch, int* __restrict__ gbeg) {
    int b = threadIdx.x;
    if (b > N_B) return;
    if (b == N_B) { gbeg[N_B] = N_NODES; return; }
    int lo = 0, hi = N_NODES;
    while (lo < hi) {
        int mid = (lo + hi) >> 1;
        if (batch[mid] < b) lo = mid + 1; else hi = mid;
    }
    gbeg[b] = lo;
}

__global__ __launch_bounds__(256) void seg_max(const float* __restrict__ gate, const int* __restrict__ gbeg,
                                               float* __restrict__ gmax) {
    int b = blockIdx.x;
    int s = gbeg[b], e = gbeg[b + 1];
    float m = -INFINITY;
    for (int i = s + threadIdx.x; i < e; i += 256) m = fmaxf(m, gate[i]);
    for (int o = 32; o > 0; o >>= 1) m = fmaxf(m, __shfl_xor(m, o, 64));
    __shared__ float red[4];
    if ((threadIdx.x & 63) == 0) red[threadIdx.x >> 6] = m;
    __syncthreads();
    if (threadIdx.x == 0) gmax[b] = fmaxf(fmaxf(red[0], red[1]), fmaxf(red[2], red[3]));
}

__global__ __launch_bounds__(256) void seg_sum(const float* __restrict__ gate, const int* __restrict__ gbeg,
                                               const float* __restrict__ gmax, float* __restrict__ gsum) {
    int b = blockIdx.x;
    int s = gbeg[b], e = gbeg[b + 1];
    float m = gmax[b];
    float acc = 0.0f;
    for (int i = s + threadIdx.x; i < e; i += 256) acc += expf(gate[i] - m);
    for (int o = 32; o > 0; o >>= 1) acc += __shfl_xor(acc, o, 64);
    __shared__ float red[4];
    if ((threadIdx.x & 63) == 0) red[threadIdx.x >> 6] = acc;
    __syncthreads();
    if (threadIdx.x == 0) gsum[b] = red[0] + red[1] + red[2] + red[3];
}

// 8 slices per graph; atomicAdd into zero-initialized gout.
__global__ __launch_bounds__(512) void seg_pool(const float* __restrict__ h, const float* __restrict__ gate,
                                                const int* __restrict__ gbeg, const float* __restrict__ gmax,
                                                const float* __restrict__ gsum, float* __restrict__ gout) {
    int b = blockIdx.x >> 3, slice = blockIdx.x & 7;
    int team = threadIdx.x >> 7;
    int f = threadIdx.x & 127;
    int s = gbeg[b], e = gbeg[b + 1];
    float m = gmax[b];
    float inv = (e > s) ? 1.0f / gsum[b] : 0.0f;
    float acc = 0.0f;
    for (int i = s + slice * 4 + team; i < e; i += 32) {
        float a = expf(gate[i] - m) * inv;
        acc = fmaf(a, h[(size_t)i * 128 + f], acc);
    }
    __shared__ float red[4][128];
    red[team][f] = acc;
    __syncthreads();
    if (team == 0) {
        float v = red[0][f] + red[1][f] + red[2][f] + red[3][f];
        atomicAdd(&gout[b * 128 + f], v);
    }
}

// ---------------- host launch ----------------

extern "C" void kernel_launch(void* const* d_in, const int* in_sizes, int n_in,
                              void* d_out, int out_size, void* d_ws, size_t ws_size,
                              hipStream_t stream) {
    const float* x     = (const float*)d_in[0];
    const int*   ei    = (const int*)d_in[1];
    const int*   batch = (const int*)d_in[2];
    const float* ea    = (const float*)d_in[3];
    const float* We1 = (const float*)d_in[4];
    const float* be1 = (const float*)d_in[5];
    const float* W1a = (const float*)d_in[6];
    const float* b1a = (const float*)d_in[7];
    const float* W1b = (const float*)d_in[8];
    const float* b1b = (const float*)d_in[9];
    const float* g1  = (const float*)d_in[10];
    const float* bn1 = (const float*)d_in[11];
    const float* We2 = (const float*)d_in[12];
    const float* be2 = (const float*)d_in[13];
    const float* W2a = (const float*)d_in[14];
    const float* b2a = (const float*)d_in[15];
    const float* W2b = (const float*)d_in[16];
    const float* b2b = (const float*)d_in[17];
    const float* g2  = (const float*)d_in[18];
    const float* bn2 = (const float*)d_in[19];
    const float* Wg1 = (const float*)d_in[20];
    const float* bg1 = (const float*)d_in[21];
    const float* Wg2 = (const float*)d_in[22];
    const float* bg2 = (const float*)d_in[23];

    float* outH = (float*)d_out;                 // [N,128] final h (also used as scratch)
    float* outG = outH + (size_t)N_NODES * 128;  // [B,128] pooled

    char* w = (char*)d_ws;
    auto carve = [&](size_t bytes) {
        void* p = (void*)w;
        w += ((bytes + 255) / 256) * 256;
        return p;
    };
    float*  bufB   = (float*)carve((size_t)N_NODES * 128 * 4);  // 51.2 MB
    float*  bufC   = (float*)carve((size_t)N_NODES * 128 * 4);  // 51.2 MB
    int4*   edata  = (int4*)carve((size_t)N_EDGES * 16);        // 25.6 MB {src, ea.x, ea.y, 0}
    int*    counts = (int*)carve((size_t)N_NODES * 4);
    int*    rp     = (int*)carve((size_t)(N_NODES + 1) * 4);
    int*    cursor = (int*)carve((size_t)N_NODES * 4);
    float*  dis    = (float*)carve((size_t)N_NODES * 4);
    float*  selfw  = (float*)carve((size_t)N_NODES * 4);
    float*  rsq    = (float*)carve((size_t)N_NODES * 4);
    float*  gate   = (float*)carve((size_t)N_NODES * 4);
    int*    bsum   = (int*)carve(128 * 4);
    float*  gmax   = (float*)carve(N_B * 4);
    float*  gsum   = (float*)carve(N_B * 4);
    int*    gbeg   = (int*)carve((N_B + 1) * 4);

    const int* src = ei;
    const int* dst = ei + N_EDGES;

    const int NB_SCAN = (N_NODES + 1023) / 1024;  // 98
    const int EB = (N_EDGES + 255) / 256;
    const int NBLK = (N_NODES + 255) / 256;
    const int WBLK = (N_NODES + 3) / 4;    // one wave per node, 4 waves/block
    const int MBLK = (N_NODES + 63) / 64;  // 1563 blocks for mfma kernels

    // Buffer plan (liveness):
    //   xb (bf16 x copy) = bufC[25.6:38.4MB] (pingA region; dead until APPNP)
    //   agg1 = bufB ; t1 = outH ; h1f = bufB (overwrites agg1), h1bf = bufC[0:25.6MB]
    //   agg2 = outH (overwrites t1) ; t2 = bufB (overwrites h1f)
    //   anchor u0 = bufC[0:25.6] (overwrites h1bf) ; pingA = bufC[25.6:51.2] ; pingB = bufB[0:25.6]
    //   esrc = bufB[25.6:32.0] (written by split_kernel after mlp2b reads bufB)
    unsigned short* h1bf  = (unsigned short*)bufC;
    unsigned* ancU  = (unsigned*)bufC;
    unsigned* pingA = ancU + (size_t)N_NODES * 64;
    unsigned* pingB = (unsigned*)bufB;
    unsigned short* xb = (unsigned short*)pingA;   // [N,64] bf16, dead before APPNP starts
    int*      esrc  = (int*)(bufB + (size_t)N_NODES * 64);

    // CSR build
    hipMemsetAsync(counts, 0, (size_t)N_NODES * 4, stream);
    hist_kernel<<<EB, 256, 0, stream>>>(dst, counts);
    deg_kernel<<<NBLK, 256, 0, stream>>>(counts, dis, selfw, rsq);
    scan1<<<NB_SCAN, 1024, 0, stream>>>(counts, rp, bsum);
    scan2<<<1, 64, 0, stream>>>(bsum, NB_SCAN);
    scan3<<<NB_SCAN, 1024, 0, stream>>>(rp, bsum, cursor);
    scatter_kernel<<<EB, 256, 0, stream>>>(src, dst, ea, cursor, edata);
    x_to_bf<<<(N_NODES * 16 + 255) / 256, 256, 0, stream>>>((const float4*)x, (uint2*)xb);

    // conv1
    conv1_gather<<<WBLK, 256, 0, stream>>>(x, (const unsigned*)xb, rp, edata, We1, be1, bufB);
    mlp_mfma<64, true, false, 0, false><<<MBLK, 256, 0, stream>>>(bufB, W1a, b1a, nullptr, nullptr, outH, nullptr, nullptr);
    mlp_mfma<128, true, true, 1, false><<<MBLK, 256, 0, stream>>>(outH, W1b, b1b, g1, bn1, bufB, h1bf, nullptr);

    // conv2
    conv2_gather<<<WBLK, 256, 0, stream>>>(bufB, (const unsigned*)h1bf, rp, edata, We2, be2, outH);
    mlp_mfma<128, true, false, 0, false><<<MBLK, 256, 0, stream>>>(outH, W2a, b2a, nullptr, nullptr, bufB, nullptr, nullptr);
    // anchor u0 = dis * LN(h2)
    mlp_mfma<128, false, true, 2, true><<<MBLK, 256, 0, stream>>>(bufB, W2b, b2b, g2, bn2, nullptr, (unsigned short*)ancU, dis);

    // compact 4B src stream for APPNP (bufB upper region is free from here on)
    split_kernel<<<EB, 256, 0, stream>>>(edata, esrc);

    // APPNP in u-space: steps 1..15 bf16 ping-pong; step 16 unscales to f32 outH.
    const unsigned* cur = ancU;
    for (int k = 1; k <= K_ITER - 1; k++) {
        unsigned* dstbuf = (k & 1) ? pingA : pingB;
        appnp_step_u<false><<<WBLK, 256, 0, stream>>>(cur, ancU, dstbuf, nullptr, rp, esrc, selfw, nullptr);
        cur = dstbuf;
    }
    appnp_step_u<true><<<WBLK, 256, 0, stream>>>(cur, ancU, nullptr, outH, rp, esrc, selfw, rsq);

    // pooling on outH
    gate_mfma<<<MBLK, 256, 0, stream>>>(outH, Wg1, bg1, Wg2, bg2, gate);
    seg_begin<<<1, 128, 0, stream>>>(batch, gbeg);
    seg_max<<<N_B, 256, 0, stream>>>(gate, gbeg, gmax);
    seg_sum<<<N_B, 256, 0, stream>>>(gate, gbeg, gmax, gsum);
    hipMemsetAsync(outG, 0, (size_t)N_B * 128 * 4, stream);
    seg_pool<<<N_B * 8, 512, 0, stream>>>(outH, gate, gbeg, gmax, gsum, outG);
}